// Round 8
// baseline (295.045 us; speedup 1.0000x reference)
//
#include <hip/hip_runtime.h>
#include <hip/hip_bf16.h>
#include <cstdint>

#define SS 4096
#define DD 1024

typedef __attribute__((ext_vector_type(4))) float f32x4;
typedef __attribute__((ext_vector_type(8))) short bf16x8;

__device__ __forceinline__ float bf2f(unsigned short u) {
    union { unsigned int i; float f; } v; v.i = ((unsigned int)u) << 16; return v.f;
}
__device__ __forceinline__ unsigned short f2bf(float f) {
    union { float f; unsigned int i; } v; v.f = f;
    unsigned int r = v.i + 0x7fff + ((v.i >> 16) & 1);  // round-nearest-even
    return (unsigned short)(r >> 16);
}

// ---------------- batched fp32 -> bf16 cast (z selects tensor) ----------------
__global__ void cast3_f32_bf16(const float* __restrict__ q, const float* __restrict__ k,
                               const float* __restrict__ v,
                               unsigned short* __restrict__ oq, unsigned short* __restrict__ ok,
                               unsigned short* __restrict__ ov) {
    const int z = blockIdx.z;
    const float* in = (z == 0) ? q : (z == 1) ? k : v;
    unsigned short* out = (z == 0) ? oq : (z == 1) ? ok : ov;
    int i = (blockIdx.x * blockDim.x + threadIdx.x) * 4;
    float4 val = *(const float4*)(in + i);
    ushort4 o;
    o.x = f2bf(val.x); o.y = f2bf(val.y); o.z = f2bf(val.z); o.w = f2bf(val.w);
    *(ushort4*)(out + i) = o;
}

// ---------------- batched W [K][N] fp32 -> Wt [N][K] bf16 transpose ----------------
__global__ void transpose3_w(const float* __restrict__ wq, const float* __restrict__ wk,
                             const float* __restrict__ wv,
                             unsigned short* __restrict__ oq, unsigned short* __restrict__ ok,
                             unsigned short* __restrict__ ov) {
    const int z = blockIdx.z;
    const float* in = (z == 0) ? wq : (z == 1) ? wk : wv;
    unsigned short* out = (z == 0) ? oq : (z == 1) ? ok : ov;
    __shared__ float tile[32][33];
    int tx = threadIdx.x, ty = threadIdx.y;           // (32, 8)
    int c0 = blockIdx.x * 32, r0 = blockIdx.y * 32;
#pragma unroll
    for (int i = 0; i < 4; ++i) {
        int r = r0 + ty + i * 8;
        tile[ty + i * 8][tx] = in[(size_t)r * DD + c0 + tx];
    }
    __syncthreads();
#pragma unroll
    for (int i = 0; i < 4; ++i) {
        int r = ty + i * 8;
        out[(size_t)(c0 + r) * DD + r0 + tx] = f2bf(tile[tx][r]);
    }
}

// ---------------- V [S][D] bf16, rowsum[S] -> Vst [D][S] bf16 = V^T / rowsum ----------------
__global__ void scale_transpose_v(const unsigned short* __restrict__ vin,
                                  const float* __restrict__ rowsum,
                                  unsigned short* __restrict__ out) {
    __shared__ float tile[32][33];
    int tx = threadIdx.x, ty = threadIdx.y;           // (32, 8)
    int d0 = blockIdx.x * 32, j0 = blockIdx.y * 32;
#pragma unroll
    for (int i = 0; i < 4; ++i) {
        int j = j0 + ty + i * 8;
        tile[ty + i * 8][tx] = bf2f(vin[(size_t)j * DD + d0 + tx]) * (1.0f / rowsum[j]);
    }
    __syncthreads();
#pragma unroll
    for (int i = 0; i < 4; ++i) {
        int d = ty + i * 8;
        out[(size_t)(d0 + d) * SS + j0 + tx] = f2bf(tile[tx][d]);
    }
}

// ---------------- out += P (split-K reduce), float4 ----------------
__global__ void add_out(float* __restrict__ out, const float* __restrict__ P) {
    int i = (blockIdx.x * blockDim.x + threadIdx.x) * 4;
    float4 a = *(const float4*)(out + i);
    float4 b = *(const float4*)(P + i);
    a.x += b.x; a.y += b.y; a.z += b.z; a.w += b.w;
    *(float4*)(out + i) = a;
}

// ========== triple-buffered counted-vmcnt bf16 GEMM core (BK=32) ==========
// C[BMxBN tile] = A[M,K] @ Bt[N,K]^T over k in [k_begin, k_begin+k_len)
// WMxWN waves, per-wave (BM/WM)x(BN/WN) output.
// LDS: 3 buffers (A+B); 4-slot chunk swizzle keyed on (row>>1)&3 -> uniform
// 2-way bank access (free per m136). Pre-swizzled global source + swizzled
// read, LINEAR gload_lds dest (rule #21; bijective for any row-derived key).
// Pipeline per iter: stage(t+2) -> ds_read(t) -> MFMA -> sched_barrier(0)
// -> s_waitcnt vmcnt(4) (t+1 landed, t+2 in flight; tail: vmcnt(0))
// -> s_barrier. 4 gload_lds/thread/stage => vmcnt(4) == "tile t+1 landed".
// MODE 0: C = acc + bias[col], store bf16
// MODE 1: C = exp(acc/1024), store bf16, atomicAdd row sums into rowsum[]
// MODE 2: C = acc, plain fp32 store
template <int BM, int BN, int WM, int WN, int MODE>
__device__ __forceinline__ void gemm_pipe_core(
        const unsigned short* __restrict__ A, const unsigned short* __restrict__ Bt,
        const float* __restrict__ bias, float* __restrict__ rowsum,
        void* __restrict__ Cout, int N, int K, int k_begin, int k_len,
        int bm, int bn) {
    constexpr int T = WM * WN * 64;
    constexpr int M_REP = BM / WM / 16;
    constexpr int N_REP = BN / WN / 16;
    constexpr int A_ELEMS = BM * 32;
    constexpr int B_ELEMS = BN * 32;

    __shared__ unsigned short As[3][A_ELEMS];
    __shared__ unsigned short Bs[3][B_ELEMS];

    const int t = threadIdx.x;
    const int l = t & 63;
    const int wid = t >> 6;
    const int wm = wid / WN, wn = wid % WN;
    const int lr = l & 15;
    const int lk = (l >> 4) * 8;        // k elem offset; 16B chunk g = lk>>3
    const int g = lk >> 3;

    f32x4 acc[M_REP][N_REP] = {};

    const size_t a_base = (size_t)bm * BM * K;
    const size_t b_base = (size_t)bn * BN * K;

    auto stage = [&](int buf, int k0) {
#pragma unroll
        for (int i = 0; i < A_ELEMS / (T * 8); ++i) {
            const int idx = i * T + t;
            const int row = idx >> 2;
            const int sch = (idx & 3) ^ ((row >> 1) & 3);  // inverse-swizzled source
            __builtin_amdgcn_global_load_lds(
                (const __attribute__((address_space(1))) void*)(A + a_base + (size_t)row * K + k0 + sch * 8),
                (__attribute__((address_space(3))) void*)(&As[buf][idx * 8]), 16, 0, 0);
        }
#pragma unroll
        for (int i = 0; i < B_ELEMS / (T * 8); ++i) {
            const int idx = i * T + t;
            const int row = idx >> 2;
            const int sch = (idx & 3) ^ ((row >> 1) & 3);
            __builtin_amdgcn_global_load_lds(
                (const __attribute__((address_space(1))) void*)(Bt + b_base + (size_t)row * K + k0 + sch * 8),
                (__attribute__((address_space(3))) void*)(&Bs[buf][idx * 8]), 16, 0, 0);
        }
    };

    // swizzled fragment read: LDS chunk = g ^ ((row>>1)&3)
    auto frag = [&](const unsigned short* L, int row) -> bf16x8 {
        return *(const bf16x8*)&L[row * 32 + ((g ^ ((row >> 1) & 3)) * 8)];
    };

    const int NT = k_len / 32;

    stage(0, k_begin);
    stage(1, k_begin + 32);
    asm volatile("s_waitcnt vmcnt(4)" ::: "memory");   // tile 0 landed
    __builtin_amdgcn_s_barrier();

    int b0 = 0, b1 = 1, b2 = 2;
    for (int kt = 0; kt < NT; ++kt) {
        const bool pf = (kt + 2 < NT);
        if (pf) stage(b2, k_begin + (kt + 2) * 32);

        const unsigned short* Ac = As[b0];
        const unsigned short* Bc = Bs[b0];
        bf16x8 af[M_REP], bfr[N_REP];
#pragma unroll
        for (int m = 0; m < M_REP; ++m)
            af[m] = frag(Ac, wm * (BM / WM) + m * 16 + lr);
#pragma unroll
        for (int n = 0; n < N_REP; ++n)
            bfr[n] = frag(Bc, wn * (BN / WN) + n * 16 + lr);
#pragma unroll
        for (int m = 0; m < M_REP; ++m)
#pragma unroll
            for (int n = 0; n < N_REP; ++n)
                acc[m][n] = __builtin_amdgcn_mfma_f32_16x16x32_bf16(af[m], bfr[n], acc[m][n], 0, 0, 0);

        __builtin_amdgcn_sched_barrier(0);             // pin reads/MFMA before barrier
        if (pf) asm volatile("s_waitcnt vmcnt(4)" ::: "memory");  // t+1 landed, t+2 in flight
        else    asm volatile("s_waitcnt vmcnt(0)" ::: "memory");  // tail drain
        __builtin_amdgcn_s_barrier();
        int tmp = b0; b0 = b1; b1 = b2; b2 = tmp;
    }

    // epilogue: C/D layout col = lane&15, row = (lane>>4)*4 + r
    const int r0 = (l >> 4) * 4;
    const int cc = l & 15;
#pragma unroll
    for (int m = 0; m < M_REP; ++m) {
        const int grow = bm * BM + wm * (BM / WM) + m * 16 + r0;
        if (MODE == 1) {
            float rs[4] = {0.f, 0.f, 0.f, 0.f};
#pragma unroll
            for (int n = 0; n < N_REP; ++n) {
                const int gcol = bn * BN + wn * (BN / WN) + n * 16 + cc;
#pragma unroll
                for (int r = 0; r < 4; ++r) {
                    float e = __expf(acc[m][n][r] * (1.0f / 1024.0f));
                    rs[r] += e;
                    ((unsigned short*)Cout)[(size_t)(grow + r) * N + gcol] = f2bf(e);
                }
            }
#pragma unroll
            for (int r = 0; r < 4; ++r) {
                float v = rs[r];
                v += __shfl_xor(v, 1, 64);
                v += __shfl_xor(v, 2, 64);
                v += __shfl_xor(v, 4, 64);
                v += __shfl_xor(v, 8, 64);
                if (cc == 0) atomicAdd(&rowsum[grow + r], v);
            }
        } else {
#pragma unroll
            for (int n = 0; n < N_REP; ++n) {
                const int gcol = bn * BN + wn * (BN / WN) + n * 16 + cc;
#pragma unroll
                for (int r = 0; r < 4; ++r) {
                    float v = acc[m][n][r];
                    if (MODE == 0) {
                        v += bias[gcol];
                        ((unsigned short*)Cout)[(size_t)(grow + r) * N + gcol] = f2bf(v);
                    } else {
                        ((float*)Cout)[(size_t)(grow + r) * N + gcol] = v;
                    }
                }
            }
        }
    }
}

// 3 projections, one dispatch: 128^2 tiles, grid (8,32,3) = 768 blocks (3/CU).
__global__ __launch_bounds__(256) void proj3(
        const unsigned short* __restrict__ Xq, const unsigned short* __restrict__ Xk,
        const unsigned short* __restrict__ Xv,
        const unsigned short* __restrict__ Wqt, const unsigned short* __restrict__ Wkt,
        const unsigned short* __restrict__ Wvt,
        const float* __restrict__ bq, const float* __restrict__ bk, const float* __restrict__ bv,
        unsigned short* __restrict__ Qb, unsigned short* __restrict__ Kb,
        unsigned short* __restrict__ Vb) {
    const int z = blockIdx.z;
    const unsigned short* A  = (z == 0) ? Xq  : (z == 1) ? Xk  : Xv;
    const unsigned short* Bt = (z == 0) ? Wqt : (z == 1) ? Wkt : Wvt;
    const float* bias        = (z == 0) ? bq  : (z == 1) ? bk  : bv;
    unsigned short* C        = (z == 0) ? Qb  : (z == 1) ? Kb  : Vb;
    gemm_pipe_core<128, 128, 2, 2, 0>(A, Bt, bias, nullptr, C, DD, DD, 0, DD,
                                      blockIdx.y, blockIdx.x);
}

// scores + exp + rowsum: 256^2 tiles (halves staging bytes/FLOP), 512 threads,
// grid 256 = exactly 1/CU, XCD-chunked decode (xcd = bid%8 gets 2 bm-rows).
__global__ __launch_bounds__(512) void gemm_scores(
        const unsigned short* __restrict__ Qb, const unsigned short* __restrict__ Kb,
        float* __restrict__ rowsum, unsigned short* __restrict__ E) {
    const int bid = blockIdx.x;
    const int xcd = bid & 7, idx = bid >> 3;
    const int bm = xcd * 2 + (idx >> 4);
    const int bn = idx & 15;
    gemm_pipe_core<256, 256, 2, 4, 1>(Qb, Kb, nullptr, rowsum, E, SS, DD, 0, DD, bm, bn);
}

// out = E @ Vst^T, split-K=2 into disjoint fp32 buffers (z=0 -> out, z=1 -> P).
__global__ __launch_bounds__(256) void gemm_out(
        const unsigned short* __restrict__ E, const unsigned short* __restrict__ Vst,
        float* __restrict__ out, float* __restrict__ P) {
    float* dst = (blockIdx.z == 0) ? out : P;
    gemm_pipe_core<128, 128, 2, 2, 2>(E, Vst, nullptr, nullptr, dst, DD, SS,
                                      blockIdx.z * (SS / 2), SS / 2,
                                      blockIdx.y, blockIdx.x);
}

extern "C" void kernel_launch(void* const* d_in, const int* in_sizes, int n_in,
                              void* d_out, int out_size, void* d_ws, size_t ws_size,
                              hipStream_t stream) {
    const float* query = (const float*)d_in[0];
    const float* key   = (const float*)d_in[1];
    const float* value = (const float*)d_in[2];
    const float* Wq    = (const float*)d_in[3];
    const float* bq    = (const float*)d_in[4];
    const float* Wk    = (const float*)d_in[5];
    const float* bk    = (const float*)d_in[6];
    const float* Wv    = (const float*)d_in[7];
    const float* bv    = (const float*)d_in[8];
    float* out = (float*)d_out;

    char* ws = (char*)d_ws;
    const size_t SD = (size_t)SS * DD;           // 4M elems
    const size_t DDsz = (size_t)DD * DD;         // 1M elems

    // phase-1 region [0, 32MB): X (24MB) + Wt (6MB); later overlaid by E (32MB)
    unsigned short* Xq  = (unsigned short*)ws;
    unsigned short* Xk  = Xq + SD;
    unsigned short* Xv  = Xk + SD;
    unsigned short* Wqt = Xv + SD;
    unsigned short* Wkt = Wqt + DDsz;
    unsigned short* Wvt = Wkt + DDsz;
    unsigned short* E   = (unsigned short*)ws;   // overlays X/W once they are dead
    unsigned short* Qb  = (unsigned short*)(ws + ((size_t)32 << 20));
    unsigned short* Kb  = Qb + SD;
    unsigned short* Vb  = Kb + SD;
    unsigned short* Vst = Vb + SD;
    float* rowsum = (float*)(ws + ((size_t)64 << 20));
    // split-K partial: overlays Qb+Kb (dead after gemm_scores). 16MB fp32.
    float* P = (float*)(ws + ((size_t)32 << 20));

    hipMemsetAsync(rowsum, 0, SS * sizeof(float), stream);

    cast3_f32_bf16<<<dim3(SS * DD / 4 / 256, 1, 3), 256, 0, stream>>>(query, key, value, Xq, Xk, Xv);

    transpose3_w<<<dim3(32, 32, 3), dim3(32, 8), 0, stream>>>(Wq, Wk, Wv, Wqt, Wkt, Wvt);

    proj3<<<dim3(DD / 128, SS / 128, 3), 256, 0, stream>>>(Xq, Xk, Xv, Wqt, Wkt, Wvt,
                                                           bq, bk, bv, Qb, Kb, Vb);

    gemm_scores<<<dim3((SS / 256) * (SS / 256)), 512, 0, stream>>>(Qb, Kb, rowsum, E);

    scale_transpose_v<<<dim3(DD / 32, SS / 32), dim3(32, 8), 0, stream>>>(Vb, rowsum, Vst);

    gemm_out<<<dim3(DD / 128, SS / 128, 2), 256, 0, stream>>>(E, Vst, out, P);

    add_out<<<SS * DD / 4 / 256, 256, 0, stream>>>(out, P);
}

// Round 11
// 268.407 us; speedup vs baseline: 1.0992x; 1.0992x over previous
//
#include <hip/hip_runtime.h>
#include <hip/hip_bf16.h>
#include <cstdint>

#define SS 4096
#define DD 1024

typedef __attribute__((ext_vector_type(4))) float f32x4;
typedef __attribute__((ext_vector_type(8))) short bf16x8;

#define GLDS(gptr, lptr) \
    __builtin_amdgcn_global_load_lds( \
        (const __attribute__((address_space(1))) void*)(gptr), \
        (__attribute__((address_space(3))) void*)(lptr), 16, 0, 0)

__device__ __forceinline__ float bf2f(unsigned short u) {
    union { unsigned int i; float f; } v; v.i = ((unsigned int)u) << 16; return v.f;
}
__device__ __forceinline__ unsigned short f2bf(float f) {
    union { float f; unsigned int i; } v; v.f = f;
    unsigned int r = v.i + 0x7fff + ((v.i >> 16) & 1);  // round-nearest-even
    return (unsigned short)(r >> 16);
}

// ---------------- batched fp32 -> bf16 cast (z selects tensor) ----------------
__global__ void cast3_f32_bf16(const float* __restrict__ q, const float* __restrict__ k,
                               const float* __restrict__ v,
                               unsigned short* __restrict__ oq, unsigned short* __restrict__ ok,
                               unsigned short* __restrict__ ov) {
    const int z = blockIdx.z;
    const float* in = (z == 0) ? q : (z == 1) ? k : v;
    unsigned short* out = (z == 0) ? oq : (z == 1) ? ok : ov;
    int i = (blockIdx.x * blockDim.x + threadIdx.x) * 4;
    float4 val = *(const float4*)(in + i);
    ushort4 o;
    o.x = f2bf(val.x); o.y = f2bf(val.y); o.z = f2bf(val.z); o.w = f2bf(val.w);
    *(ushort4*)(out + i) = o;
}

// ---------------- batched W [K][N] fp32 -> Wt [N][K] bf16 transpose ----------------
__global__ void transpose3_w(const float* __restrict__ wq, const float* __restrict__ wk,
                             const float* __restrict__ wv,
                             unsigned short* __restrict__ oq, unsigned short* __restrict__ ok,
                             unsigned short* __restrict__ ov) {
    const int z = blockIdx.z;
    const float* in = (z == 0) ? wq : (z == 1) ? wk : wv;
    unsigned short* out = (z == 0) ? oq : (z == 1) ? ok : ov;
    __shared__ float tile[32][33];
    int tx = threadIdx.x, ty = threadIdx.y;           // (32, 8)
    int c0 = blockIdx.x * 32, r0 = blockIdx.y * 32;
#pragma unroll
    for (int i = 0; i < 4; ++i) {
        int r = r0 + ty + i * 8;
        tile[ty + i * 8][tx] = in[(size_t)r * DD + c0 + tx];
    }
    __syncthreads();
#pragma unroll
    for (int i = 0; i < 4; ++i) {
        int r = ty + i * 8;
        out[(size_t)(c0 + r) * DD + r0 + tx] = f2bf(tile[tx][r]);
    }
}

// ---------------- V [S][D] bf16, rowsum[S] -> Vst [D][S] bf16 = V^T / rowsum ----------------
__global__ void scale_transpose_v(const unsigned short* __restrict__ vin,
                                  const float* __restrict__ rowsum,
                                  unsigned short* __restrict__ out) {
    __shared__ float tile[32][33];
    int tx = threadIdx.x, ty = threadIdx.y;           // (32, 8)
    int d0 = blockIdx.x * 32, j0 = blockIdx.y * 32;
#pragma unroll
    for (int i = 0; i < 4; ++i) {
        int j = j0 + ty + i * 8;
        tile[ty + i * 8][tx] = bf2f(vin[(size_t)j * DD + d0 + tx]) * (1.0f / rowsum[j]);
    }
    __syncthreads();
#pragma unroll
    for (int i = 0; i < 4; ++i) {
        int d = ty + i * 8;
        out[(size_t)(d0 + d) * SS + j0 + tx] = f2bf(tile[tx][d]);
    }
}

// ---------------- out += bf16 partials P1+P2+P3 (split-K reduce) ----------------
__global__ void add_out3(float* __restrict__ out, const unsigned short* __restrict__ p1,
                         const unsigned short* __restrict__ p2,
                         const unsigned short* __restrict__ p3) {
    int i = (blockIdx.x * blockDim.x + threadIdx.x) * 4;
    float4 a = *(const float4*)(out + i);
    ushort4 u1 = *(const ushort4*)(p1 + i);
    ushort4 u2 = *(const ushort4*)(p2 + i);
    ushort4 u3 = *(const ushort4*)(p3 + i);
    a.x += bf2f(u1.x) + bf2f(u2.x) + bf2f(u3.x);
    a.y += bf2f(u1.y) + bf2f(u2.y) + bf2f(u3.y);
    a.z += bf2f(u1.z) + bf2f(u2.z) + bf2f(u3.z);
    a.w += bf2f(u1.w) + bf2f(u2.w) + bf2f(u3.w);
    *(float4*)(out + i) = a;
}

// ============ 256x256 8-phase 3-buffer bf16 GEMM core (BK=32) ============
// C = A[M,K] @ Bt[N,K]^T over k in [k_begin, k_begin+k_len). 512 thr = 8 waves
// (2M x 4N), per-wave C = 128x64, acc[8][4]. LDS: 3 bufs x (A 16KB + B 16KB)
// = 96KB. Swizzle: chunk ^= (row>>1)&3 (r8-validated zero-conflict), linear
// gload_lds dest + inverse-swizzled source + swizzled read (rule #21).
// Iteration = 2 K-tiles x 4 phases. Phase = {ds_read subtile; stage 1
// quarter-tile (1 load/thr); s_barrier; lgkmcnt(0)+sched_barrier; setprio(1)
// 8 MFMA setprio(0); [p4/p8: vmcnt(4)]; s_barrier}. Tile staged exactly 2
// half-iters before first read (bufs rotate mod 3) -> 5-8 phases of latency
// cover; vmcnt(4) leaves the current half's 4 stages in flight (T4).
// MODE 0: C = acc + bias[col], bf16 store.  MODE 1: C = exp(acc/1024), bf16
// store + rowsum atomics.  MODE 2: plain store, fp32 or bf16 per `bf16st`.
template <int MODE>
__device__ __forceinline__ void gemm8_core(
        const unsigned short* __restrict__ A, const unsigned short* __restrict__ Bt,
        const float* __restrict__ bias, float* __restrict__ rowsum,
        void* __restrict__ Cout, int N, int K, int k_begin, int k_len,
        int bm, int bn, int bf16st) {
    __shared__ unsigned short As[3][256 * 32];
    __shared__ unsigned short Bs[3][256 * 32];

    const int t = threadIdx.x;          // 0..511
    const int l = t & 63;
    const int wid = t >> 6;
    const int wr = wid >> 2;            // 0..1
    const int wc = wid & 3;             // 0..3
    const int lr = l & 15;
    const int g = l >> 4;               // 16B k-chunk 0..3

    f32x4 acc[8][4] = {};

    const size_t a_base = (size_t)bm * 256 * K;
    const size_t b_base = (size_t)bn * 256 * K;

    auto stage_unit = [&](int buf, int k0, int u) {
        const int i = u & 1;
        const int idx = i * 512 + t;
        const int row = idx >> 2;
        const int ch = idx & 3;
        const int sch = ch ^ ((row >> 1) & 3);
        if (u < 2) {
            GLDS(A + a_base + (size_t)row * K + k0 + sch * 8, &As[buf][idx * 8]);
        } else {
            GLDS(Bt + b_base + (size_t)row * K + k0 + sch * 8, &Bs[buf][idx * 8]);
        }
    };

    auto fragA = [&](int buf, int row) -> bf16x8 {
        return *(const bf16x8*)&As[buf][row * 32 + ((g ^ ((row >> 1) & 3)) * 8)];
    };
    auto fragB = [&](int buf, int row) -> bf16x8 {
        return *(const bf16x8*)&Bs[buf][row * 32 + ((g ^ ((row >> 1) & 3)) * 8)];
    };

    const int NT = k_len / 32;
    const int ar = wr * 128;
    const int br = wc * 64;

#define BARRIER() __builtin_amdgcn_s_barrier()
#define LGKM0()  do { asm volatile("s_waitcnt lgkmcnt(0)" ::: "memory"); \
                      __builtin_amdgcn_sched_barrier(0); } while (0)
#define MFMA(i, n, av, bv) acc[i][n] = __builtin_amdgcn_mfma_f32_16x16x32_bf16(av, bv, acc[i][n], 0, 0, 0)

    // prologue: tiles 0 and 1 fully staged; tile0 guaranteed landed.
#pragma unroll
    for (int u = 0; u < 4; ++u) stage_unit(0, k_begin, u);
#pragma unroll
    for (int u = 0; u < 4; ++u) stage_unit(1, k_begin + 32, u);
    asm volatile("s_waitcnt vmcnt(4)" ::: "memory");
    BARRIER();

    // one half-iteration: compute tile in bufR (4 phases), stage tile kS->bufS
    auto half_iter = [&](int bufR, int bufS, int kS, bool do_stage) {
        bf16x8 a0, a1, a2, a3, b00, b01, b10, b11;
        // ---- phase 1: quadrant (m0, n0)
        a0 = fragA(bufR, ar + 0 + lr);  a1 = fragA(bufR, ar + 16 + lr);
        a2 = fragA(bufR, ar + 32 + lr); a3 = fragA(bufR, ar + 48 + lr);
        b00 = fragB(bufR, br + 0 + lr); b01 = fragB(bufR, br + 16 + lr);
        if (do_stage) stage_unit(bufS, kS, 0);
        BARRIER(); LGKM0();
        __builtin_amdgcn_s_setprio(1);
        MFMA(0, 0, a0, b00); MFMA(1, 0, a1, b00); MFMA(2, 0, a2, b00); MFMA(3, 0, a3, b00);
        MFMA(0, 1, a0, b01); MFMA(1, 1, a1, b01); MFMA(2, 1, a2, b01); MFMA(3, 1, a3, b01);
        __builtin_amdgcn_s_setprio(0);
        BARRIER();
        // ---- phase 2: quadrant (m0, n1) — reuse a0..a3
        b10 = fragB(bufR, br + 32 + lr); b11 = fragB(bufR, br + 48 + lr);
        if (do_stage) stage_unit(bufS, kS, 1);
        BARRIER(); LGKM0();
        __builtin_amdgcn_s_setprio(1);
        MFMA(0, 2, a0, b10); MFMA(1, 2, a1, b10); MFMA(2, 2, a2, b10); MFMA(3, 2, a3, b10);
        MFMA(0, 3, a0, b11); MFMA(1, 3, a1, b11); MFMA(2, 3, a2, b11); MFMA(3, 3, a3, b11);
        __builtin_amdgcn_s_setprio(0);
        BARRIER();
        // ---- phase 3: quadrant (m1, n1) — reload A, reuse b10/b11
        a0 = fragA(bufR, ar + 64 + lr);  a1 = fragA(bufR, ar + 80 + lr);
        a2 = fragA(bufR, ar + 96 + lr);  a3 = fragA(bufR, ar + 112 + lr);
        if (do_stage) stage_unit(bufS, kS, 2);
        BARRIER(); LGKM0();
        __builtin_amdgcn_s_setprio(1);
        MFMA(4, 2, a0, b10); MFMA(5, 2, a1, b10); MFMA(6, 2, a2, b10); MFMA(7, 2, a3, b10);
        MFMA(4, 3, a0, b11); MFMA(5, 3, a1, b11); MFMA(6, 3, a2, b11); MFMA(7, 3, a3, b11);
        __builtin_amdgcn_s_setprio(0);
        BARRIER();
        // ---- phase 4: quadrant (m1, n0) — b00/b01 still live; no ds_read
        if (do_stage) stage_unit(bufS, kS, 3);
        BARRIER(); LGKM0();
        __builtin_amdgcn_s_setprio(1);
        MFMA(4, 0, a0, b00); MFMA(5, 0, a1, b00); MFMA(6, 0, a2, b00); MFMA(7, 0, a3, b00);
        MFMA(4, 1, a0, b01); MFMA(5, 1, a1, b01); MFMA(6, 1, a2, b01); MFMA(7, 1, a3, b01);
        __builtin_amdgcn_s_setprio(0);
        // checkpoint: all stages older than this half's 4 must have landed
        if (do_stage) asm volatile("s_waitcnt vmcnt(4)" ::: "memory");
        else          asm volatile("s_waitcnt vmcnt(0)" ::: "memory");
        BARRIER();
    };

    int ba = 0, bb = 1, bc = 2;         // bufs of tiles t, t+1, t+2 (t+3 -> ba)
    for (int tt = 0; tt < NT; tt += 2) {
        half_iter(ba, bc, k_begin + (tt + 2) * 32, (tt + 2) < NT);
        half_iter(bb, ba, k_begin + (tt + 3) * 32, (tt + 3) < NT);
        const int na = bc, nb = ba, nc = bb;
        ba = na; bb = nb; bc = nc;
    }
#undef BARRIER
#undef LGKM0
#undef MFMA

    // ---- epilogue: C/D layout col = lane&15, row = (lane>>4)*4 + r
    const int r0 = (l >> 4) * 4;
    const int cc = l & 15;
#pragma unroll
    for (int i = 0; i < 8; ++i) {
        const int grow = bm * 256 + wr * 128 + (i >> 2) * 64 + (i & 3) * 16 + r0;
        if (MODE == 1) {
            float rs[4] = {0.f, 0.f, 0.f, 0.f};
#pragma unroll
            for (int n = 0; n < 4; ++n) {
                const int gcol = bn * 256 + wc * 64 + (n >> 1) * 32 + (n & 1) * 16 + cc;
#pragma unroll
                for (int r = 0; r < 4; ++r) {
                    float e = __expf(acc[i][n][r] * (1.0f / 1024.0f));
                    rs[r] += e;
                    ((unsigned short*)Cout)[(size_t)(grow + r) * N + gcol] = f2bf(e);
                }
            }
#pragma unroll
            for (int r = 0; r < 4; ++r) {
                float v = rs[r];
                v += __shfl_xor(v, 1, 64);
                v += __shfl_xor(v, 2, 64);
                v += __shfl_xor(v, 4, 64);
                v += __shfl_xor(v, 8, 64);
                if (cc == 0) atomicAdd(&rowsum[grow + r], v);
            }
        } else {
#pragma unroll
            for (int n = 0; n < 4; ++n) {
                const int gcol = bn * 256 + wc * 64 + (n >> 1) * 32 + (n & 1) * 16 + cc;
#pragma unroll
                for (int r = 0; r < 4; ++r) {
                    float v = acc[i][n][r];
                    if (MODE == 0) {
                        v += bias[gcol];
                        ((unsigned short*)Cout)[(size_t)(grow + r) * N + gcol] = f2bf(v);
                    } else {
                        if (bf16st) ((unsigned short*)Cout)[(size_t)(grow + r) * N + gcol] = f2bf(v);
                        else        ((float*)Cout)[(size_t)(grow + r) * N + gcol] = v;
                    }
                }
            }
        }
    }
}

// 3 projections, one dispatch: grid (4, 16, 3) = 192 blocks.
__global__ __launch_bounds__(512, 2) void proj3(
        const unsigned short* __restrict__ Xq, const unsigned short* __restrict__ Xk,
        const unsigned short* __restrict__ Xv,
        const unsigned short* __restrict__ Wqt, const unsigned short* __restrict__ Wkt,
        const unsigned short* __restrict__ Wvt,
        const float* __restrict__ bq, const float* __restrict__ bk, const float* __restrict__ bv,
        unsigned short* __restrict__ Qb, unsigned short* __restrict__ Kb,
        unsigned short* __restrict__ Vb) {
    const int z = blockIdx.z;
    const unsigned short* A  = (z == 0) ? Xq  : (z == 1) ? Xk  : Xv;
    const unsigned short* Bt = (z == 0) ? Wqt : (z == 1) ? Wkt : Wvt;
    const float* bias        = (z == 0) ? bq  : (z == 1) ? bk  : bv;
    unsigned short* C        = (z == 0) ? Qb  : (z == 1) ? Kb  : Vb;
    gemm8_core<0>(A, Bt, bias, nullptr, C, DD, DD, 0, DD, blockIdx.y, blockIdx.x, 0);
}

// scores + exp + rowsum: grid (16, 16) = 256 blocks.
__global__ __launch_bounds__(512, 2) void gemm_scores(
        const unsigned short* __restrict__ Qb, const unsigned short* __restrict__ Kb,
        float* __restrict__ rowsum, unsigned short* __restrict__ E) {
    gemm8_core<1>(Qb, Kb, nullptr, rowsum, E, SS, DD, 0, DD, blockIdx.y, blockIdx.x, 0);
}

// out = E @ Vst^T, split-K=4: z=0 -> fp32 out, z=1..3 -> bf16 partials.
__global__ __launch_bounds__(512, 2) void gemm_out(
        const unsigned short* __restrict__ E, const unsigned short* __restrict__ Vst,
        float* __restrict__ out, unsigned short* __restrict__ P1,
        unsigned short* __restrict__ P2, unsigned short* __restrict__ P3) {
    const int z = blockIdx.z;
    void* dst = (z == 0) ? (void*)out : (z == 1) ? (void*)P1 : (z == 2) ? (void*)P2 : (void*)P3;
    gemm8_core<2>(E, Vst, nullptr, nullptr, dst, DD, SS, z * (SS / 4), SS / 4,
                  blockIdx.y, blockIdx.x, z != 0);
}

extern "C" void kernel_launch(void* const* d_in, const int* in_sizes, int n_in,
                              void* d_out, int out_size, void* d_ws, size_t ws_size,
                              hipStream_t stream) {
    const float* query = (const float*)d_in[0];
    const float* key   = (const float*)d_in[1];
    const float* value = (const float*)d_in[2];
    const float* Wq    = (const float*)d_in[3];
    const float* bq    = (const float*)d_in[4];
    const float* Wk    = (const float*)d_in[5];
    const float* bk    = (const float*)d_in[6];
    const float* Wv    = (const float*)d_in[7];
    const float* bv    = (const float*)d_in[8];
    float* out = (float*)d_out;

    char* ws = (char*)d_ws;
    const size_t SD = (size_t)SS * DD;           // 4M elems
    const size_t DDsz = (size_t)DD * DD;         // 1M elems

    // phase-1 region [0, 32MB): X (24MB) + Wt (6MB); later overlaid by E (32MB)
    unsigned short* Xq  = (unsigned short*)ws;
    unsigned short* Xk  = Xq + SD;
    unsigned short* Xv  = Xk + SD;
    unsigned short* Wqt = Xv + SD;
    unsigned short* Wkt = Wqt + DDsz;
    unsigned short* Wvt = Wkt + DDsz;
    unsigned short* E   = (unsigned short*)ws;   // overlays X/W once they are dead
    unsigned short* Qb  = (unsigned short*)(ws + ((size_t)32 << 20));
    unsigned short* Kb  = Qb + SD;
    unsigned short* Vb  = Kb + SD;
    unsigned short* Vst = Vb + SD;
    float* rowsum = (float*)(ws + ((size_t)64 << 20));
    // split-K bf16 partials overlay Qb/Kb/Vb (dead before gemm_out)
    unsigned short* P1 = Qb;
    unsigned short* P2 = Kb;
    unsigned short* P3 = Vb;

    hipMemsetAsync(rowsum, 0, SS * sizeof(float), stream);

    cast3_f32_bf16<<<dim3(SS * DD / 4 / 256, 1, 3), 256, 0, stream>>>(query, key, value, Xq, Xk, Xv);

    transpose3_w<<<dim3(32, 32, 3), dim3(32, 8), 0, stream>>>(Wq, Wk, Wv, Wqt, Wkt, Wvt);

    proj3<<<dim3(DD / 256, SS / 256, 3), 512, 0, stream>>>(Xq, Xk, Xv, Wqt, Wkt, Wvt,
                                                           bq, bk, bv, Qb, Kb, Vb);

    gemm_scores<<<dim3(SS / 256, SS / 256), 512, 0, stream>>>(Qb, Kb, rowsum, E);

    scale_transpose_v<<<dim3(DD / 32, SS / 32), dim3(32, 8), 0, stream>>>(Vb, rowsum, Vst);

    gemm_out<<<dim3(DD / 256, SS / 256, 4), 512, 0, stream>>>(E, Vst, out, P1, P2, P3);

    add_out3<<<SS * DD / 4 / 256, 256, 0, stream>>>(out, P1, P2, P3);
}